// Round 7
// baseline (655.632 us; speedup 1.0000x reference)
//
#include <hip/hip_runtime.h>
#include <math.h>

// WorldNet rollout: B=2048 rows, T=128 serial steps, 9-layer MLP + reward.
// R8 = R7 chassis (ROWS=4, grid 512 = 2 blocks/CU, lgkm-only barriers,
// reg-held x_t, a-prefetch, bias-fold, fmed3 clip, wave-local tail) plus:
//  (a) KS-minimization on cross-wave layers (DPP pairs 111->40, acc-init
//      40->26; weight regs unchanged: regs = K*NW*RS/NT regardless of KS):
//      L3 KS=2/NP=128, L4 KS=4/NP=64, L5 RS=2/KS=4, L6 RS=2/KS=8.
//  (b) wave-local HEAD: L0 RS=4/KS=4 (J=40, +30 regs), L1 RS=4/KS=2 (+6) ->
//      barriers 8 -> 6; step = long col-private stretch (L7,L8,residual,
//      reward, a-stage, L0, L1) + 6-barrier cross-wave middle (L2..L6).
//  (c) ACCS partial accumulators for RPL=1 layers (L0: 4, L1: 2) to break
//      the J-deep dependent FMA chain (R4's serial-chain mistake).
// Budget: 166 w + 11 b + ~28 temps ~= 205 floats < 256-reg 2-wave/SIMD cap.
// Spill tripwire: FETCH_SIZE must stay ~37 MB (R5 spill showed 2.27 GB).

#define TSTEPS 128
#define NB     2048
#define NST    115
#define NACT   39
#define NINF   154
#define NOUTF  116
constexpr int NT   = 256;
constexpr int ROWS = 4;

// ---- DPP reduction (VALU pipe, no DS ops) ----
template<int CTRL>
__device__ __forceinline__ float dpp_add(float x) {
  int y = __builtin_amdgcn_update_dpp(0, __float_as_int(x), CTRL, 0xF, 0xF, true);
  return x + __int_as_float(y);
}
// Sum over the KS-lane group in the low lane bits (KS in {2,4,8,16}).
template<int KS>
__device__ __forceinline__ float kreduce(float a) {
  if constexpr (KS >= 2)  a = dpp_add<0xB1>(a);   // xor1  quad_perm[1,0,3,2]
  if constexpr (KS >= 4)  a = dpp_add<0x4E>(a);   // xor2  quad_perm[2,3,0,1]
  if constexpr (KS >= 8)  a = dpp_add<0x141>(a);  // xor7  ROW_HALF_MIRROR
  if constexpr (KS >= 16) a = dpp_add<0x140>(a);  // xor15 ROW_MIRROR
  return a;
}

// Barrier that drains only LDS ops (NOT vmcnt): all cross-wave handoff is LDS;
// global stores are fire-and-forget.
__device__ __forceinline__ void barrier_lds() {
  asm volatile("s_waitcnt lgkmcnt(0)\n\ts_barrier" ::: "memory");
}
// Same-wave LDS write->read fence (no barrier).
__device__ __forceinline__ void wait_lds() {
  asm volatile("s_waitcnt lgkmcnt(0)" ::: "memory");
}

// Thread map: tid = kp + KS*(cg + NP*rg).  Thread holds weights W[k][n] for
// k = kp + KS*j (j<J) and n = cg + c*NP (c<NC); computes RPL = ROWS/RS rows.
// RS=4 => rg == wave id => layer is wave-local (column handoff stays in-wave).
// Bias pre-scaled by 1/KS (exact for pow2 KS): acc init carries it; the
// KS-way butterfly sums the copies back to exactly b.
template<int K, int NW, int NP, int NC, int KS, int RS, int J>
__device__ __forceinline__ void wload(const float* __restrict__ Wg,
                                      const float* __restrict__ bg,
                                      float (&w)[J][NC], float (&b)[NC], int tid) {
  static_assert(NP * KS * RS == NT, "bad cfg");
  static_assert(J * KS >= K, "bad J");
  constexpr float BS = 1.0f / (float)KS;
  const int kp = tid % KS, rest = tid / KS, cg = rest % NP;
#pragma unroll
  for (int j = 0; j < J; ++j)
#pragma unroll
    for (int c = 0; c < NC; ++c) {
      const int k = kp + KS * j, n = cg + c * NP;
      w[j][c] = (k < K && n < NW) ? Wg[k * NW + n] : 0.f;   // zero-pad
    }
#pragma unroll
  for (int c = 0; c < NC; ++c) {
    const int n = cg + c * NP;
    b[c] = (n < NW) ? bg[n] * BS : 0.f;
  }
}

// ACCS: number of partial accumulators along j (breaks the dependent FMA
// chain for RPL=1 layers; summed before kreduce — reassociation only).
template<int K, int NW, int NP, int NC, int KS, int RS, int J, bool CLIP, int ACCS>
__device__ __forceinline__ void lrun(const float (&w)[J][NC], const float (&b)[NC],
                                     const float* __restrict__ in,
                                     float* __restrict__ out, int tid) {
  constexpr int RPL = ROWS / RS;
  const int kp = tid % KS, rest = tid / KS, cg = rest % NP, rg = rest / NP;
  float acc[NC][RPL][ACCS];
#pragma unroll
  for (int c = 0; c < NC; ++c)
#pragma unroll
    for (int r = 0; r < RPL; ++r) {
      acc[c][r][0] = b[c];   // bias folded in (b/KS)
#pragma unroll
      for (int a = 1; a < ACCS; ++a) acc[c][r][a] = 0.f;
    }

#pragma unroll
  for (int j = 0; j < J; ++j) {
    const int k = kp + KS * j;
    const float* ap = in + k * ROWS + rg * RPL;
    float av[RPL];
    if constexpr (RPL == 4) {
      float4 t = *(const float4*)ap; av[0]=t.x; av[1]=t.y; av[2]=t.z; av[3]=t.w;
    } else if constexpr (RPL == 2) {
      float2 t = *(const float2*)ap; av[0]=t.x; av[1]=t.y;
    } else {
      av[0] = *ap;
    }
#pragma unroll
    for (int c = 0; c < NC; ++c)
#pragma unroll
      for (int r = 0; r < RPL; ++r) acc[c][r][j % ACCS] += w[j][c] * av[r];
  }
#pragma unroll
  for (int c = 0; c < NC; ++c)
#pragma unroll
    for (int r = 0; r < RPL; ++r) {
      float s = acc[c][r][0];
#pragma unroll
      for (int a = 1; a < ACCS; ++a) s += acc[c][r][a];
      acc[c][r][0] = kreduce<KS>(s);
    }

  if (kp == 0) {
#pragma unroll
    for (int c = 0; c < NC; ++c) {
      const int n = cg + c * NP;
      bool ok = true;
      if constexpr (NP * NC > NW) ok = (n < NW);
      if (ok) {
        float ov[RPL];
#pragma unroll
        for (int r = 0; r < RPL; ++r) {
          float v = acc[c][r][0];
          if constexpr (CLIP) v = __builtin_amdgcn_fmed3f(v, 0.f, 6.f);
          ov[r] = v;
        }
        float* op = out + n * ROWS + rg * RPL;
        if constexpr (RPL == 4)      *(float4*)op = make_float4(ov[0], ov[1], ov[2], ov[3]);
        else if constexpr (RPL == 2) *(float2*)op = make_float2(ov[0], ov[1]);
        else                         *op = ov[0];
      }
    }
  }
}

__global__ __launch_bounds__(NT, 2)
void worldnet_kernel(const float* __restrict__ u,
                     const float* __restrict__ W0, const float* __restrict__ b0,
                     const float* __restrict__ W1, const float* __restrict__ b1,
                     const float* __restrict__ W2, const float* __restrict__ b2,
                     const float* __restrict__ W3, const float* __restrict__ b3,
                     const float* __restrict__ W4, const float* __restrict__ b4,
                     const float* __restrict__ W5, const float* __restrict__ b5,
                     const float* __restrict__ W6, const float* __restrict__ b6,
                     const float* __restrict__ W7, const float* __restrict__ b7,
                     const float* __restrict__ W8, const float* __restrict__ b8,
                     const float* __restrict__ Wr, const float* __restrict__ br,
                     float* __restrict__ out) {
  __shared__ __align__(16) float sIN[160 * ROWS];  // x(115) | acts(39) | zero pad(6)
  __shared__ __align__(16) float sA[128 * ROWS];
  __shared__ __align__(16) float sB[128 * ROWS];
  const int tid = threadIdx.x, wv = tid >> 6, lane = tid & 63;

  // ---- per-thread register weights ----
  // w regs: 40+8+8+32+32+16+4+2+16+8 = 166 (+11 bias).
  float w0[40][1], w1[8][1], w2[8][1], w3[32][1], w4[32][1],
        w5[16][1], w6[4][1], w7[2][1], w8[8][2],  wR[8][1];
  float c0[1], c1[1], c2[1], c3[1], c4[1], c5[1], c6[1], c7[1], c8[2], cR[1];
  wload<154, 16,   16, 1,  4, 4, 40>(W0, b0, w0, c0, tid);  // wave-local
  wload< 16, 32,   32, 1,  2, 4,  8>(W1, b1, w1, c1, tid);  // wave-local
  wload< 32, 64,   64, 1,  4, 1,  8>(W2, b2, w2, c2, tid);
  wload< 64, 128, 128, 1,  2, 1, 32>(W3, b3, w3, c3, tid);
  wload<128, 64,   64, 1,  4, 1, 32>(W4, b4, w4, c4, tid);
  wload< 64, 32,   32, 1,  4, 2, 16>(W5, b5, w5, c5, tid);  // RS=2
  wload< 32, 16,   16, 1,  8, 2,  4>(W6, b6, w6, c6, tid);  // RS=2
  wload< 16,  8,    8, 1,  8, 4,  2>(W7, b7, w7, c7, tid);  // wave-local
  wload<  8, 115,  64, 2,  1, 4,  8>(W8, b8, w8, c8, tid);  // wave-local, n==lane
  wload<115,  3,    4, 1, 16, 4,  8>(Wr, br, wR, cR, tid);  // wave-local

  const size_t row = (size_t)blockIdx.x * ROWS + wv;   // wave wv owns row wv
  const float* urow = u + row * (size_t)(TSTEPS * NINF);
  float* orow = out + row * (size_t)(TSTEPS * NOUTF);

  // x0 = u[:,0,:115]: stage into sIN + regs, store x_0, zero pad [154,160).
  // All column-private.
  float xr0 = urow[lane];
  float xr1 = (lane < NST - 64) ? urow[lane + 64] : 0.f;
  sIN[lane * ROWS + wv] = xr0;
  orow[lane] = xr0;
  if (lane < NST - 64) {
    sIN[(lane + 64) * ROWS + wv] = xr1;
    orow[lane + 64] = xr1;
  }
  if (lane < 160 - NINF) sIN[(NINF + lane) * ROWS + wv] = 0.f;
  float a_pre = (lane < NACT) ? urow[NST + lane] : 0.f;   // prefetch a_0
  wait_lds();

#pragma unroll 1
  for (int t = 0; t < TSTEPS; ++t) {
    float* ot = orow + (size_t)t * NOUTF;

    // stage a_t (own column), then issue prefetch of a_{t+1}
    if (lane < NACT) sIN[(NST + lane) * ROWS + wv] = a_pre;
    {
      const int tn = (t < TSTEPS - 1) ? t + 1 : t;
      a_pre = (lane < NACT) ? urow[tn * NINF + NST + lane] : 0.f;
    }
    wait_lds();

    // ---- wave-local head (own column only; no barriers) ----
    lrun<154, 16,  16, 1, 4, 4, 40, true, 4>(w0, c0, sIN, sA, tid); wait_lds();
    lrun< 16, 32,  32, 1, 2, 4,  8, true, 2>(w1, c1, sA, sB, tid);
    barrier_lds();                                                        // 1

    // ---- cross-wave middle ----
    lrun< 32, 64,   64, 1, 4, 1,  8, true, 1>(w2, c2, sB, sA, tid); barrier_lds(); // 2
    lrun< 64, 128, 128, 1, 2, 1, 32, true, 1>(w3, c3, sA, sB, tid); barrier_lds(); // 3
    lrun<128, 64,   64, 1, 4, 1, 32, true, 1>(w4, c4, sB, sA, tid); barrier_lds(); // 4
    lrun< 64, 32,   32, 1, 4, 2, 16, true, 1>(w5, c5, sA, sB, tid); barrier_lds(); // 5
    lrun< 32, 16,   16, 1, 8, 2,  4, true, 1>(w6, c6, sB, sA, tid); barrier_lds(); // 6

    // ---- wave-local tail (own column only; no barriers) ----
    // L7: reads sA col wv (L6 out, covered by barrier 6), writes sB col wv.
    lrun< 16,  8,   8, 1, 8, 4,  2, true, 1>(w7, c7, sA, sB, tid);
    wait_lds();

    // L8 inline (RS=4, KS=1, n==lane): delta straight into registers.
    // All lanes read the same sB address per j -> LDS broadcast.
    {
      float d0 = c8[0], d1 = c8[1];
#pragma unroll
      for (int j = 0; j < 8; ++j) {
        const float hv = sB[j * ROWS + wv];
        d0 += w8[j][0] * hv;
        d1 += w8[j][1] * hv;
      }
      float xn0 = xr0 + d0;
      float xn1 = xr1 + d1;              // lane>=51: garbage, never stored
      const int i0 = lane * ROWS + wv, i1 = (lane + 64) * ROWS + wv;
      sIN[i0] = xn0;
      if (lane < NST - 64) sIN[i1] = xn1;
      xr0 = xn0;
      if (lane < NST - 64) xr1 = xn1;
      if (t < TSTEPS - 1) {
        float* on = ot + NOUTF;          // out row t+1
        on[lane] = xn0;
        if (lane < NST - 64) on[lane + 64] = xn1;
      }
      wait_lds();   // own-column residual writes visible to own-wave reward

      // reward_t = -||x_{t+1} @ Wr + br||; kp=lane%16, c=lane/16 (c<3, pad 0).
      // Wr rows k>=115 are zero regs, so reading sIN k in [115,128) (own acts
      // region, possibly already holding a_{t+1}) is harmless.
      const int kp = lane & 15;
      float p = cR[0];                   // bias pre-scaled by 1/16
#pragma unroll
      for (int j = 0; j < 8; ++j) {
        const int k = kp + 16 * j;
        p += wR[j][0] * sIN[k * ROWS + wv];
      }
      p = kreduce<16>(p);
      float s0 = __shfl(p, 0, 64);
      float s1 = __shfl(p, 16, 64);
      float s2 = __shfl(p, 32, 64);
      if (lane == 0) ot[NST] = -sqrtf(s0 * s0 + s1 * s1 + s2 * s2);
    }
    // Loop-top stage-a + L0/L1 are column-private: no step-boundary barrier.
  }
}

extern "C" void kernel_launch(void* const* d_in, const int* in_sizes, int n_in,
                              void* d_out, int out_size, void* d_ws, size_t ws_size,
                              hipStream_t stream) {
  const float* u  = (const float*)d_in[0];
  const float* W0 = (const float*)d_in[1];  const float* b0 = (const float*)d_in[2];
  const float* W1 = (const float*)d_in[3];  const float* b1 = (const float*)d_in[4];
  const float* W2 = (const float*)d_in[5];  const float* b2 = (const float*)d_in[6];
  const float* W3 = (const float*)d_in[7];  const float* b3 = (const float*)d_in[8];
  const float* W4 = (const float*)d_in[9];  const float* b4 = (const float*)d_in[10];
  const float* W5 = (const float*)d_in[11]; const float* b5 = (const float*)d_in[12];
  const float* W6 = (const float*)d_in[13]; const float* b6 = (const float*)d_in[14];
  const float* W7 = (const float*)d_in[15]; const float* b7 = (const float*)d_in[16];
  const float* W8 = (const float*)d_in[17]; const float* b8 = (const float*)d_in[18];
  const float* Wr = (const float*)d_in[19]; const float* br = (const float*)d_in[20];
  float* out = (float*)d_out;
  (void)in_sizes; (void)n_in; (void)out_size; (void)d_ws; (void)ws_size;

  dim3 grid(NB / ROWS), block(NT);
  hipLaunchKernelGGL(worldnet_kernel, grid, block, 0, stream,
                     u, W0, b0, W1, b1, W2, b2, W3, b3, W4, b4,
                     W5, b5, W6, b6, W7, b7, W8, b8, Wr, br, out);
}

// Round 8
// 619.286 us; speedup vs baseline: 1.0587x; 1.0587x over previous
//
#include <hip/hip_runtime.h>
#include <math.h>

// WorldNet rollout: B=2048 rows, T=128 serial steps, 9-layer MLP + reward.
// R9: 4 barriers/step. Wave-local head (L0,L1) AND tail (L5..L8,res,reward,
// stage); only L2,L3,L4 cross-wave, using R7's NC=2 maps (R8 lesson: NC=1
// doubles ds_read_b128 count and eats the barrier savings). Local-layer KS
// chosen to minimize reads+DPP jointly (L0: KS=8/NC=2 = 20 reads + 6 dpp,
// not R8's KS=4 = 40 reads + 2 dpp). Buffer chain sIN->A->B->A->B->A->B->A
// ->B->regs; all local-stretch accesses are column-wv-private (race audit in
// comments below). Budget ~220 unified regs < 256 cap (2 waves/SIMD).
// Chassis: ROWS=4, grid 512 = 2 blocks/CU, lgkm-only barriers, reg-held x_t,
// a-prefetch, bias-fold (b/KS), fmed3 clip, ACCS partial accumulators.

#define TSTEPS 128
#define NB     2048
#define NST    115
#define NACT   39
#define NINF   154
#define NOUTF  116
constexpr int NT   = 256;
constexpr int ROWS = 4;

// ---- DPP reduction (VALU pipe, no DS ops) ----
template<int CTRL>
__device__ __forceinline__ float dpp_add(float x) {
  int y = __builtin_amdgcn_update_dpp(0, __float_as_int(x), CTRL, 0xF, 0xF, true);
  return x + __int_as_float(y);
}
// Sum over the KS-lane group in the low lane bits (KS in {1,2,4,8,16}).
template<int KS>
__device__ __forceinline__ float kreduce(float a) {
  if constexpr (KS >= 2)  a = dpp_add<0xB1>(a);   // xor1  quad_perm[1,0,3,2]
  if constexpr (KS >= 4)  a = dpp_add<0x4E>(a);   // xor2  quad_perm[2,3,0,1]
  if constexpr (KS >= 8)  a = dpp_add<0x141>(a);  // xor7  ROW_HALF_MIRROR
  if constexpr (KS >= 16) a = dpp_add<0x140>(a);  // xor15 ROW_MIRROR
  return a;
}

// Barrier that drains only LDS ops (NOT vmcnt): all cross-wave handoff is LDS;
// global stores are fire-and-forget.
__device__ __forceinline__ void barrier_lds() {
  asm volatile("s_waitcnt lgkmcnt(0)\n\ts_barrier" ::: "memory");
}
// Same-wave LDS write->read fence (no barrier); DS ops of a wave complete in
// order, the drain makes the just-written values visible to own-wave reads.
__device__ __forceinline__ void wait_lds() {
  asm volatile("s_waitcnt lgkmcnt(0)" ::: "memory");
}

// Thread map: tid = kp + KS*(cg + NP*rg).  Thread holds weights W[k][n] for
// k = kp + KS*j (j<J) and n = cg + c*NP (c<NC); computes RPL = ROWS/RS rows.
// RS=4 => rg == wave id => layer is wave-local (column handoff stays in-wave).
// Bias pre-scaled by 1/KS (exact for pow2 KS): acc init carries it; the
// KS-way butterfly sums the copies back to exactly b.
template<int K, int NW, int NP, int NC, int KS, int RS, int J>
__device__ __forceinline__ void wload(const float* __restrict__ Wg,
                                      const float* __restrict__ bg,
                                      float (&w)[J][NC], float (&b)[NC], int tid) {
  static_assert(NP * KS * RS == NT, "bad cfg");
  static_assert(J * KS >= K, "bad J");
  constexpr float BS = 1.0f / (float)KS;
  const int kp = tid % KS, rest = tid / KS, cg = rest % NP;
#pragma unroll
  for (int j = 0; j < J; ++j)
#pragma unroll
    for (int c = 0; c < NC; ++c) {
      const int k = kp + KS * j, n = cg + c * NP;
      w[j][c] = (k < K && n < NW) ? Wg[k * NW + n] : 0.f;   // zero-pad
    }
#pragma unroll
  for (int c = 0; c < NC; ++c) {
    const int n = cg + c * NP;
    b[c] = (n < NW) ? bg[n] * BS : 0.f;
  }
}

// ACCS: number of partial accumulators along j (breaks the dependent FMA
// chain for RPL=1 layers; summed before kreduce — reassociation only).
template<int K, int NW, int NP, int NC, int KS, int RS, int J, bool CLIP, int ACCS>
__device__ __forceinline__ void lrun(const float (&w)[J][NC], const float (&b)[NC],
                                     const float* __restrict__ in,
                                     float* __restrict__ out, int tid) {
  constexpr int RPL = ROWS / RS;
  const int kp = tid % KS, rest = tid / KS, cg = rest % NP, rg = rest / NP;
  float acc[NC][RPL][ACCS];
#pragma unroll
  for (int c = 0; c < NC; ++c)
#pragma unroll
    for (int r = 0; r < RPL; ++r) {
      acc[c][r][0] = b[c];   // bias folded in (b/KS)
#pragma unroll
      for (int a = 1; a < ACCS; ++a) acc[c][r][a] = 0.f;
    }

#pragma unroll
  for (int j = 0; j < J; ++j) {
    const int k = kp + KS * j;
    const float* ap = in + k * ROWS + rg * RPL;
    float av[RPL];
    if constexpr (RPL == 4) {
      float4 t = *(const float4*)ap; av[0]=t.x; av[1]=t.y; av[2]=t.z; av[3]=t.w;
    } else if constexpr (RPL == 2) {
      float2 t = *(const float2*)ap; av[0]=t.x; av[1]=t.y;
    } else {
      av[0] = *ap;
    }
#pragma unroll
    for (int c = 0; c < NC; ++c)
#pragma unroll
      for (int r = 0; r < RPL; ++r) acc[c][r][j % ACCS] += w[j][c] * av[r];
  }
#pragma unroll
  for (int c = 0; c < NC; ++c)
#pragma unroll
    for (int r = 0; r < RPL; ++r) {
      float s = acc[c][r][0];
#pragma unroll
      for (int a = 1; a < ACCS; ++a) s += acc[c][r][a];
      acc[c][r][0] = kreduce<KS>(s);
    }

  if (kp == 0) {
#pragma unroll
    for (int c = 0; c < NC; ++c) {
      const int n = cg + c * NP;
      bool ok = true;
      if constexpr (NP * NC > NW) ok = (n < NW);
      if (ok) {
        float ov[RPL];
#pragma unroll
        for (int r = 0; r < RPL; ++r) {
          float v = acc[c][r][0];
          if constexpr (CLIP) v = __builtin_amdgcn_fmed3f(v, 0.f, 6.f);
          ov[r] = v;
        }
        float* op = out + n * ROWS + rg * RPL;
        if constexpr (RPL == 4)      *(float4*)op = make_float4(ov[0], ov[1], ov[2], ov[3]);
        else if constexpr (RPL == 2) *(float2*)op = make_float2(ov[0], ov[1]);
        else                         *op = ov[0];
      }
    }
  }
}

__global__ __launch_bounds__(NT, 2)
void worldnet_kernel(const float* __restrict__ u,
                     const float* __restrict__ W0, const float* __restrict__ b0,
                     const float* __restrict__ W1, const float* __restrict__ b1,
                     const float* __restrict__ W2, const float* __restrict__ b2,
                     const float* __restrict__ W3, const float* __restrict__ b3,
                     const float* __restrict__ W4, const float* __restrict__ b4,
                     const float* __restrict__ W5, const float* __restrict__ b5,
                     const float* __restrict__ W6, const float* __restrict__ b6,
                     const float* __restrict__ W7, const float* __restrict__ b7,
                     const float* __restrict__ W8, const float* __restrict__ b8,
                     const float* __restrict__ Wr, const float* __restrict__ br,
                     float* __restrict__ out) {
  __shared__ __align__(16) float sIN[160 * ROWS];  // x(115) | acts(39) | zero pad(6)
  __shared__ __align__(16) float sA[128 * ROWS];
  __shared__ __align__(16) float sB[128 * ROWS];
  const int tid = threadIdx.x, wv = tid >> 6, lane = tid & 63;

  // ---- per-thread register weights ----
  // w regs: L0 40 + L1 8 + L2 8 + L3 32 + L4 32 + L5 32 + L6 8 + L7 2
  //         + L8 16 + R 8 = 186 (+14 bias).
  float w0[20][2], w1[8][1], w2[8][1], w3[16][2], w4[16][2],
        w5[16][2], w6[8][1], w7[2][1], w8[8][2],  wR[8][1];
  float c0[2], c1[1], c2[1], c3[2], c4[2], c5[2], c6[1], c7[1], c8[2], cR[1];
  wload<154, 16,   8, 2,  8, 4, 20>(W0, b0, w0, c0, tid);  // wave-local
  wload< 16, 32,  32, 1,  2, 4,  8>(W1, b1, w1, c1, tid);  // wave-local
  wload< 32, 64,  64, 1,  4, 1,  8>(W2, b2, w2, c2, tid);  // cross-wave
  wload< 64, 128, 64, 2,  4, 1, 16>(W3, b3, w3, c3, tid);  // cross-wave (R7 map)
  wload<128, 64,  32, 2,  8, 1, 16>(W4, b4, w4, c4, tid);  // cross-wave (R7 map)
  wload< 64, 32,  16, 2,  4, 4, 16>(W5, b5, w5, c5, tid);  // wave-local
  wload< 32, 16,  16, 1,  4, 4,  8>(W6, b6, w6, c6, tid);  // wave-local
  wload< 16,  8,   8, 1,  8, 4,  2>(W7, b7, w7, c7, tid);  // wave-local
  wload<  8, 115, 64, 2,  1, 4,  8>(W8, b8, w8, c8, tid);  // wave-local, n==lane
  wload<115,  3,   4, 1, 16, 4,  8>(Wr, br, wR, cR, tid);  // wave-local

  const size_t row = (size_t)blockIdx.x * ROWS + wv;   // wave wv owns row wv
  const float* urow = u + row * (size_t)(TSTEPS * NINF);
  float* orow = out + row * (size_t)(TSTEPS * NOUTF);

  // x0 = u[:,0,:115]: stage into sIN + regs, store x_0, zero pad [154,160).
  // All column-private.
  float xr0 = urow[lane];
  float xr1 = (lane < NST - 64) ? urow[lane + 64] : 0.f;
  sIN[lane * ROWS + wv] = xr0;
  orow[lane] = xr0;
  if (lane < NST - 64) {
    sIN[(lane + 64) * ROWS + wv] = xr1;
    orow[lane + 64] = xr1;
  }
  if (lane < 160 - NINF) sIN[(NINF + lane) * ROWS + wv] = 0.f;
  float a_pre = (lane < NACT) ? urow[NST + lane] : 0.f;   // prefetch a_0
  wait_lds();

#pragma unroll 1
  for (int t = 0; t < TSTEPS; ++t) {
    float* ot = orow + (size_t)t * NOUTF;

    // stage a_t (own column), then issue prefetch of a_{t+1}
    if (lane < NACT) sIN[(NST + lane) * ROWS + wv] = a_pre;
    {
      const int tn = (t < TSTEPS - 1) ? t + 1 : t;
      a_pre = (lane < NACT) ? urow[tn * NINF + NST + lane] : 0.f;
    }
    wait_lds();

    // ---- wave-local head (column wv only; no barriers) ----
    // L0: sIN->sA (own col; x from own residual/init, acts from own stage).
    lrun<154, 16,   8, 2, 8, 4, 20, true, 2>(w0, c0, sIN, sA, tid); wait_lds();
    // L1: sA->sB (own col).
    lrun< 16, 32,  32, 1, 2, 4,  8, true, 2>(w1, c1, sA, sB, tid);
    barrier_lds();                                                        // 1

    // ---- cross-wave middle (R7 NC=2 maps: b128 reads amortized) ----
    lrun< 32, 64,  64, 1, 4, 1,  8, true, 1>(w2, c2, sB, sA, tid); barrier_lds(); // 2
    lrun< 64, 128, 64, 2, 4, 1, 16, true, 1>(w3, c3, sA, sB, tid); barrier_lds(); // 3
    lrun<128, 64,  32, 2, 8, 1, 16, true, 1>(w4, c4, sB, sA, tid); barrier_lds(); // 4

    // ---- wave-local tail (column wv only; no barriers) ----
    // L5: sA->sB (sA col wv complete per barrier 4).
    lrun< 64, 32,  16, 2, 4, 4, 16, true, 2>(w5, c5, sA, sB, tid); wait_lds();
    // L6: sB->sA (own col).
    lrun< 32, 16,  16, 1, 4, 4,  8, true, 2>(w6, c6, sB, sA, tid); wait_lds();
    // L7: sA->sB (own col).
    lrun< 16,  8,   8, 1, 8, 4,  2, true, 1>(w7, c7, sA, sB, tid); wait_lds();

    // L8 inline (RS=4, KS=1, n==lane): delta straight into registers.
    // All lanes read the same sB address per j -> LDS broadcast.
    {
      float d0 = c8[0], d1 = c8[1];
#pragma unroll
      for (int j = 0; j < 8; ++j) {
        const float hv = sB[j * ROWS + wv];
        d0 += w8[j][0] * hv;
        d1 += w8[j][1] * hv;
      }
      float xn0 = xr0 + d0;
      float xn1 = xr1 + d1;              // lane>=51: garbage, never stored
      const int i0 = lane * ROWS + wv, i1 = (lane + 64) * ROWS + wv;
      sIN[i0] = xn0;
      if (lane < NST - 64) sIN[i1] = xn1;
      xr0 = xn0;
      if (lane < NST - 64) xr1 = xn1;
      if (t < TSTEPS - 1) {
        float* on = ot + NOUTF;          // out row t+1
        on[lane] = xn0;
        if (lane < NST - 64) on[lane + 64] = xn1;
      }
      wait_lds();   // own-column residual writes visible to own-wave reward

      // reward_t = -||x_{t+1} @ Wr + br||; kp=lane%16, c=lane/16 (c<3, pad 0).
      // Wr rows k>=115 are zero regs, so reading sIN k in [115,128) (own acts
      // region, possibly already holding a_{t+1} next iter) is harmless.
      const int kp = lane & 15;
      float p = cR[0];                   // bias pre-scaled by 1/16
#pragma unroll
      for (int j = 0; j < 8; ++j) {
        const int k = kp + 16 * j;
        p += wR[j][0] * sIN[k * ROWS + wv];
      }
      p = kreduce<16>(p);
      float s0 = __shfl(p, 0, 64);
      float s1 = __shfl(p, 16, 64);
      float s2 = __shfl(p, 32, 64);
      if (lane == 0) ot[NST] = -sqrtf(s0 * s0 + s1 * s1 + s2 * s2);
    }
    // Loop-top stage-a + L0/L1 are column-private; a racing wave parks at
    // barrier 1 until all waves finish their local stretches (lgkm drained).
  }
}

extern "C" void kernel_launch(void* const* d_in, const int* in_sizes, int n_in,
                              void* d_out, int out_size, void* d_ws, size_t ws_size,
                              hipStream_t stream) {
  const float* u  = (const float*)d_in[0];
  const float* W0 = (const float*)d_in[1];  const float* b0 = (const float*)d_in[2];
  const float* W1 = (const float*)d_in[3];  const float* b1 = (const float*)d_in[4];
  const float* W2 = (const float*)d_in[5];  const float* b2 = (const float*)d_in[6];
  const float* W3 = (const float*)d_in[7];  const float* b3 = (const float*)d_in[8];
  const float* W4 = (const float*)d_in[9];  const float* b4 = (const float*)d_in[10];
  const float* W5 = (const float*)d_in[11]; const float* b5 = (const float*)d_in[12];
  const float* W6 = (const float*)d_in[13]; const float* b6 = (const float*)d_in[14];
  const float* W7 = (const float*)d_in[15]; const float* b7 = (const float*)d_in[16];
  const float* W8 = (const float*)d_in[17]; const float* b8 = (const float*)d_in[18];
  const float* Wr = (const float*)d_in[19]; const float* br = (const float*)d_in[20];
  float* out = (float*)d_out;
  (void)in_sizes; (void)n_in; (void)out_size; (void)d_ws; (void)ws_size;

  dim3 grid(NB / ROWS), block(NT);
  hipLaunchKernelGGL(worldnet_kernel, grid, block, 0, stream,
                     u, W0, b0, W1, b1, W2, b2, W3, b3, W4, b4,
                     W5, b5, W6, b6, W7, b7, W8, b8, Wr, br, out);
}